// Round 11
// baseline (971.192 us; speedup 1.0000x reference)
//
#include <hip/hip_runtime.h>
#include <math.h>

#define BATCH 512
#define TT    1024
#define FF    128
#define UU    50
#define ZN    200            // 4*UU
#define NP    208            // padded N (13*16)
#define NTL   13             // N tiles of 16
#define CH    32             // timesteps per chunk
#define NCH   32             // TT/CH
#define ZPAD  (CH * ZN + 64) // chunk buffer + tail pad (lanes>=50 spill-read)

typedef __attribute__((ext_vector_type(8))) short bhalf8;
typedef __attribute__((ext_vector_type(4))) float f32x4;
typedef __attribute__((ext_vector_type(2))) float f32x2;

__device__ __forceinline__ float rcp_fast(float x) {
    return __builtin_amdgcn_rcpf(x);
}
__device__ __forceinline__ float sigmoid_fast(float x) {
    return rcp_fast(1.0f + __builtin_amdgcn_exp2f(-1.442695041f * x));
}
__device__ __forceinline__ float tanh_fast(float x) {
    float e = __builtin_amdgcn_exp2f(2.885390082f * x);
    return fmaf(-2.0f, rcp_fast(e + 1.0f), 1.0f);
}
__device__ __forceinline__ unsigned short bf16_rtn(float x) {
    unsigned int u = __float_as_uint(x);
    unsigned int r = u + 0x7FFFu + ((u >> 16) & 1u);
    return (unsigned short)(r >> 16);
}
__device__ __forceinline__ float bf16_f32(unsigned short h) {
    return __uint_as_float(((unsigned int)h) << 16);
}
__device__ __forceinline__ void cvt8(const float4 a, const float4 b,
                                     bhalf8& hi, bhalf8& lo) {
    float v0 = a.x, v1 = a.y, v2 = a.z, v3 = a.w;
    float v4 = b.x, v5 = b.y, v6 = b.z, v7 = b.w;
    unsigned short h0 = bf16_rtn(v0), h1 = bf16_rtn(v1), h2 = bf16_rtn(v2), h3 = bf16_rtn(v3);
    unsigned short h4 = bf16_rtn(v4), h5 = bf16_rtn(v5), h6 = bf16_rtn(v6), h7 = bf16_rtn(v7);
    hi[0]=(short)h0; hi[1]=(short)h1; hi[2]=(short)h2; hi[3]=(short)h3;
    hi[4]=(short)h4; hi[5]=(short)h5; hi[6]=(short)h6; hi[7]=(short)h7;
    lo[0]=(short)bf16_rtn(v0 - bf16_f32(h0)); lo[1]=(short)bf16_rtn(v1 - bf16_f32(h1));
    lo[2]=(short)bf16_rtn(v2 - bf16_f32(h2)); lo[3]=(short)bf16_rtn(v3 - bf16_f32(h3));
    lo[4]=(short)bf16_rtn(v4 - bf16_f32(h4)); lo[5]=(short)bf16_rtn(v5 - bf16_f32(h5));
    lo[6]=(short)bf16_rtn(v6 - bf16_f32(h6)); lo[7]=(short)bf16_rtn(v7 - bf16_f32(h7));
}

// ---------------- Prep: Kt_hi/Kt_lo[NP][FF] bf16 (transposed, hi/lo split) -------
__global__ void prep_kt_kernel(const float* __restrict__ K,
                               unsigned short* __restrict__ kt_hi,
                               unsigned short* __restrict__ kt_lo) {
    const int c = threadIdx.x;
    if (c >= NP) return;
    for (int k = 0; k < FF; ++k) {
        float v = (c < ZN) ? K[k * ZN + c] : 0.0f;
        unsigned short h = bf16_rtn(v);
        float lo = v - bf16_f32(h);
        kt_hi[c * FF + k] = h;
        kt_lo[c * FF + k] = bf16_rtn(lo);
    }
}

// ---------------- Fused producer/consumer LSTM ----------------------------------
// 512 blocks x 2 waves. Wave 1 (producer): MFMA-GEMM of x@K+bias for chunk it
// (32 steps) into zlds[it&1], permuted [t][u*4+g] at write. Wave 0 (consumer):
// r10-style register scan of chunk it-1 from zlds[(it-1)&1]. One barrier per
// chunk (33 total). zx never touches HBM (was 419 MB write + re-read).
// Scan wave has no global loads in flight -> barrier vmcnt drain is free.

#define STEPF(V) do {                                                         \
    f32x2 acc0 = {(V).x, 0.f}, acc1 = {(V).y, 0.f};                           \
    f32x2 acc2 = {(V).z, 0.f}, acc3 = {(V).w, 0.f};                           \
    _Pragma("unroll")                                                         \
    for (int k4 = 0; k4 < 12; ++k4) {                                         \
        float4 hv = ((const float4*)hbuf)[k4];   /* uniform-addr broadcast */ \
        f32x2 hp0 = {hv.x, hv.y}, hp1 = {hv.z, hv.w};                         \
        acc0 = __builtin_elementwise_fma(hp0, rr0[2 * k4], acc0);             \
        acc1 = __builtin_elementwise_fma(hp0, rr1[2 * k4], acc1);             \
        acc2 = __builtin_elementwise_fma(hp0, rr2[2 * k4], acc2);             \
        acc3 = __builtin_elementwise_fma(hp0, rr3[2 * k4], acc3);             \
        acc0 = __builtin_elementwise_fma(hp1, rr0[2 * k4 + 1], acc0);         \
        acc1 = __builtin_elementwise_fma(hp1, rr1[2 * k4 + 1], acc1);         \
        acc2 = __builtin_elementwise_fma(hp1, rr2[2 * k4 + 1], acc2);         \
        acc3 = __builtin_elementwise_fma(hp1, rr3[2 * k4 + 1], acc3);         \
    }                                                                         \
    {                                                                         \
        f32x2 hp = ((const f32x2*)hbuf)[24];     /* h[48], h[49] */           \
        acc0 = __builtin_elementwise_fma(hp, rr0[24], acc0);                  \
        acc1 = __builtin_elementwise_fma(hp, rr1[24], acc1);                  \
        acc2 = __builtin_elementwise_fma(hp, rr2[24], acc2);                  \
        acc3 = __builtin_elementwise_fma(hp, rr3[24], acc3);                  \
    }                                                                         \
    float zi = acc0.x + acc0.y, zf = acc1.x + acc1.y;                         \
    float zg = acc2.x + acc2.y, zo = acc3.x + acc3.y;                         \
    float gi = sigmoid_fast(zi), gf = sigmoid_fast(zf);                       \
    float go = sigmoid_fast(zo), gg = tanh_fast(zg);                          \
    c = gf * c + gi * gg;                                                     \
    h = go * tanh_fast(c);                                                    \
    hbuf[l] = h;                                    /* lanes>=50 unread */    \
} while (0)

#define READ4(D, R0) do {                                                     \
    _Pragma("unroll")                                                         \
    for (int s_ = 0; s_ < 4; ++s_) {                                          \
        int r_ = (R0) + s_; if (r_ > CH - 1) r_ = CH - 1;                     \
        D[s_] = *(const float4*)&zb[r_ * ZN + (l << 2)];                      \
    }                                                                         \
} while (0)

#define STEP4(S) do { STEPF(S[0]); STEPF(S[1]); STEPF(S[2]); STEPF(S[3]); } while (0)

__launch_bounds__(128, 1)
__global__ void lstm_fused2_kernel(const float* __restrict__ x,
                                   const unsigned short* __restrict__ kt_hi,
                                   const unsigned short* __restrict__ kt_lo,
                                   const float* __restrict__ bias,
                                   const float* __restrict__ R,
                                   const float* __restrict__ dw,
                                   const float* __restrict__ db,
                                   float* __restrict__ out) {
    __shared__ __align__(16) float zlds[2][ZPAD];   // 2 x 25.9 KB
    __shared__ __align__(16) float hbuf[64];

    const int tid = threadIdx.x;
    const int w = tid >> 6;          // 0 = scan (consumer), 1 = GEMM (producer)
    const int l = tid & 63;
    const int b = blockIdx.x;
    const int lrow = l & 15;
    const int lk = (l >> 4) << 3;
    const int rsub = (l >> 4) << 2;
    const bool act = (l < UU);

    // ---- per-wave setup (uniform branches; both waves' values allocated) ----
    f32x2 rr0[25], rr1[25], rr2[25], rr3[25];
    #pragma unroll
    for (int p = 0; p < 25; ++p) {
        rr0[p] = (f32x2){0.f, 0.f}; rr1[p] = (f32x2){0.f, 0.f};
        rr2[p] = (f32x2){0.f, 0.f}; rr3[p] = (f32x2){0.f, 0.f};
    }
    float dwv = 0.0f;
    int   pjx[NTL];
    float bvv[NTL];
    #pragma unroll
    for (int nt = 0; nt < NTL; ++nt) { pjx[nt] = -1; bvv[nt] = 0.f; }

    if (w == 0) {
        #pragma unroll
        for (int p = 0; p < 25; ++p) {
            if (act) {
                rr0[p] = (f32x2){ R[(2*p) * ZN + l],       R[(2*p+1) * ZN + l] };
                rr1[p] = (f32x2){ R[(2*p) * ZN + l + 50],  R[(2*p+1) * ZN + l + 50] };
                rr2[p] = (f32x2){ R[(2*p) * ZN + l + 100], R[(2*p+1) * ZN + l + 100] };
                rr3[p] = (f32x2){ R[(2*p) * ZN + l + 150], R[(2*p+1) * ZN + l + 150] };
            }
        }
        dwv = act ? dw[l] : 0.0f;
        hbuf[l] = 0.0f;
    } else {
        #pragma unroll
        for (int nt = 0; nt < NTL; ++nt) {
            const int j = nt * 16 + lrow;
            if (j < ZN) { pjx[nt] = (j % UU) * 4 + j / UU; bvv[nt] = bias[j]; }
        }
    }
    #pragma unroll
    for (int p = 0; p < 25; ++p)
        asm volatile("" : "+v"(rr0[p]), "+v"(rr1[p]), "+v"(rr2[p]), "+v"(rr3[p]));

    float h = 0.0f, c = 0.0f;
    __syncthreads();

    // ---- chunk pipeline: producer fills it, consumer drains it-1 ----
    for (int it = 0; it <= NCH; ++it) {
        if (w == 1 && it < NCH) {
            float* zb = zlds[it & 1];
            const int T0 = it * CH;
            #pragma unroll
            for (int mt = 0; mt < 2; ++mt) {
                f32x4 acc[NTL];
                #pragma unroll
                for (int nt = 0; nt < NTL; ++nt) acc[nt] = (f32x4)0.0f;
                #pragma unroll
                for (int kc = 0; kc < 4; ++kc) {
                    const float* xr = x + (size_t)((b << 10) + T0 + mt * 16 + lrow) * FF
                                        + kc * 32 + lk;
                    float4 a0 = *(const float4*)xr;
                    float4 a1 = *(const float4*)(xr + 4);
                    bhalf8 aH, aL;
                    cvt8(a0, a1, aH, aL);
                    #pragma unroll
                    for (int nt = 0; nt < NTL; ++nt) {
                        const size_t ko = (size_t)(nt * 16 + lrow) * FF + kc * 32 + lk;
                        bhalf8 bH = *(const bhalf8*)(kt_hi + ko);
                        bhalf8 bL = *(const bhalf8*)(kt_lo + ko);
                        acc[nt] = __builtin_amdgcn_mfma_f32_16x16x32_bf16(aH, bH, acc[nt], 0, 0, 0);
                        acc[nt] = __builtin_amdgcn_mfma_f32_16x16x32_bf16(aH, bL, acc[nt], 0, 0, 0);
                        acc[nt] = __builtin_amdgcn_mfma_f32_16x16x32_bf16(aL, bH, acc[nt], 0, 0, 0);
                    }
                }
                // D layout col=l&15, row=(l>>4)*4+r (verified r3+); permuted store
                #pragma unroll
                for (int nt = 0; nt < NTL; ++nt) {
                    if (pjx[nt] >= 0) {
                        #pragma unroll
                        for (int r = 0; r < 4; ++r)
                            zb[(mt * 16 + rsub + r) * ZN + pjx[nt]] = acc[nt][r] + bvv[nt];
                    }
                }
            }
        }
        if (w == 0 && it > 0) {
            const float* zb = zlds[(it - 1) & 1];
            float4 sp[4], sq[4];
            READ4(sp, 0);
            for (int g = 0; g < 4; ++g) {       // 4 x 8 = 32 steps
                READ4(sq, 8 * g + 4);
                STEP4(sp);
                READ4(sp, 8 * g + 8);           // g=3: clamped dup (dead)
                STEP4(sq);
            }
        }
        __syncthreads();
    }

    // ---- epilogue: out[b] = h . dense_w + dense_b ----
    if (w == 0) {
        float s = act ? h * dwv : 0.0f;
        #pragma unroll
        for (int off = 32; off > 0; off >>= 1) s += __shfl_down(s, off, 64);
        if (l == 0) out[b] = s + db[0];
    }
}

extern "C" void kernel_launch(void* const* d_in, const int* in_sizes, int n_in,
                              void* d_out, int out_size, void* d_ws, size_t ws_size,
                              hipStream_t stream) {
    const float* x    = (const float*)d_in[0];  // [512,1024,128]
    const float* K    = (const float*)d_in[1];  // [128,200]
    const float* R    = (const float*)d_in[2];  // [50,200]
    const float* bias = (const float*)d_in[3];  // [200]
    const float* dw   = (const float*)d_in[4];  // [50,1]
    const float* db   = (const float*)d_in[5];  // [1]
    float* out = (float*)d_out;                 // [512,1]

    const size_t kt_elems = (size_t)NP * FF;                   // 26624
    unsigned short* kt_hi = (unsigned short*)d_ws;
    unsigned short* kt_lo = kt_hi + kt_elems;                  // total 106 KB of ws

    prep_kt_kernel<<<1, 256, 0, stream>>>(K, kt_hi, kt_lo);
    lstm_fused2_kernel<<<BATCH, 128, 0, stream>>>(x, kt_hi, kt_lo, bias, R, dw, db, out);
}